// Round 3
// baseline (228.170 us; speedup 1.0000x reference)
//
#include <hip/hip_runtime.h>
#include <hip/hip_bf16.h>

#define N_ROWS 8192
#define D_DIM  4096
#define E_DIM  64
#define BR     16                 // rows per block
#define BK     256                // fp32 K elems per staged chunk
#define NCH    (D_DIM / BK)       // 16 chunks
#define NSTEP  (BK / 32)          // 8 K32-steps per chunk

typedef __attribute__((ext_vector_type(8))) short  short8;
typedef __attribute__((ext_vector_type(4))) float  floatx4;
typedef __attribute__((ext_vector_type(8))) float  float8;

// Split an fp32 vector into hi (RNE bf16) + lo (chopped bf16 of remainder).
// Bitwise-identical to the verified kernel -> identical numerics.
__device__ inline void cvt_split(const float8& f, short8& hi, short8& lo) {
#pragma unroll
  for (int j = 0; j < 8; ++j) {
    float x = f[j];
    unsigned int u  = __builtin_bit_cast(unsigned int, x);
    unsigned int rh = (u + 0x7FFFu + ((u >> 16) & 1u)) >> 16;  // RNE to bf16
    hi[j] = (short)rh;
    float hf = __builtin_bit_cast(float, rh << 16);
    float lf = x - hf;
    unsigned int ul = __builtin_bit_cast(unsigned int, lf);
    lo[j] = (short)(ul >> 16);                                  // chop
  }
}

// ---------------------------------------------------------------------------
// Prep kernel: convert W fp32 [64][4096] -> d_ws split-bf16 in FRAGMENT order.
// For K32-step s (0..127), expert tile e (0..3), plane p (hi/lo), lane l:
//   16B fragment = W rows e*16+(l&15), k = s*32+(l>>4)*8 .. +7
//   stored at ws + (s*8 + e*2 + p)*1024 + l*16          (total 1 MB)
// Main kernel's B-load is then ONE coalesced dwordx4 of a contiguous 1KB
// chunk per wave per (step,plane) — L2-resident, no cvt, no LDS.
// ---------------------------------------------------------------------------
__global__ __launch_bounds__(512) void prep_w(const void* __restrict__ xv,
                                              const void* __restrict__ wv,
                                              void* __restrict__ ws) {
  __shared__ int sflag;
  const int tid = threadIdx.x;
  if (tid < 64) {   // dtype probe (skip conversion if x/W are bf16)
    unsigned int v = ((const unsigned int*)xv)[(size_t)tid * 997];
    unsigned int e = (v >> 7) & 0xFFu;
    unsigned long long m = __ballot(e >= 100u && e <= 140u);
    if (tid == 0) sflag = (__popcll(m) > 32) ? 1 : 0;
  }
  __syncthreads();
  if (sflag) return;
  const int t    = blockIdx.x * 512 + tid;   // 64 blocks x 512 = 32768 = 128*4*64
  const int lane = t & 63;
  const int idx  = t >> 6;                    // s*4 + e
  const int s    = idx >> 2;
  const int e    = idx & 3;
  const int row  = e * 16 + (lane & 15);
  const int col  = s * 32 + (lane >> 4) * 8;
  float8 f = *(const float8*)((const float*)wv + (size_t)row * D_DIM + col);
  short8 h, l;
  cvt_split(f, h, l);
  char* d = (char*)ws + (size_t)idx * 2048 + lane * 16;
  *(short8*)d          = h;
  *(short8*)(d + 1024) = l;
}

// ---------------------------------------------------------------------------
// Main fused router: 512 blocks x 256 threads. Block = 16 rows, all 64
// experts. 4 waves: wave w -> expert tile w (16 experts), same 16 rows.
//
// fp32 path: x staged to LDS as split-bf16 (converted once per block),
// double-buffered BK=256, slot-XOR swizzle on write+read. W comes from the
// pre-converted fragment-ordered d_ws: one coalesced L2-resident dwordx4 per
// (step,plane) per wave. LDS instrs/thread/chunk: 4 writes + 16 reads (was
// 22 incl. W); W cvt eliminated. launch_bounds(256,4): VGPR<=128 ->
// 4 waves/SIMD with 2 blocks/CU (LDS ~37KB).
// ---------------------------------------------------------------------------
__global__ __launch_bounds__(256, 4) void router_kernel(
    const void* __restrict__ xv, const void* __restrict__ wv,
    const void* __restrict__ bv, const void* __restrict__ wsv,
    float* __restrict__ out) {
  __shared__ __align__(16) char sm[2][16384];   // per buffer: xh 8K | xl 8K
  __shared__ float lg[BR][E_DIM + 4];
  __shared__ int   sflag;

  const int tid = threadIdx.x;

  if (tid < 64) {   // dtype probe
    unsigned int v = ((const unsigned int*)xv)[(size_t)tid * 997];
    unsigned int e = (v >> 7) & 0xFFu;
    unsigned long long m = __ballot(e >= 100u && e <= 140u);
    if (tid == 0) sflag = (__popcll(m) > 32) ? 1 : 0;
  }
  __syncthreads();
  const int isbf = sflag;

  const int wave = tid >> 6;            // expert tile 0..3
  const int lane = tid & 63;
  const int lm   = lane & 15;           // A: row-in-tile  B: expert-in-tile
  const int t4   = lane >> 4;           // k sub-slot within 32-wide K step
  const int r0   = blockIdx.x * BR;

  floatx4 acc = {0.f, 0.f, 0.f, 0.f};

  if (!isbf) {
    // staging geometry: thread -> 16 consecutive floats of one row
    const int srow = tid >> 4;          // 0..15
    const int sc   = tid & 15;          // 16-float col group
    const float* xg = (const float*)xv + (size_t)(r0 + srow) * D_DIM + sc * 16;
    const int ws0 = srow * 512 + ((( sc * 2     ) ^ (srow & 7)) << 4);
    const int ws1 = srow * 512 + ((( sc * 2 + 1 ) ^ (srow & 7)) << 4);
    // B fragment base for this wave's expert tile (+lane*16 per fragment)
    const char* wb = (const char*)wsv + (size_t)wave * 2048 + lane * 16;
    // A read base
    const int ra  = lm * 512;
    const int axr = lm & 7;

    { // prologue: stage chunk 0
      float8 f0 = *(const float8*)xg;
      float8 f1 = *(const float8*)(xg + 8);
      short8 h, l;
      char* d = sm[0];
      cvt_split(f0, h, l); *(short8*)(d + ws0) = h; *(short8*)(d + 8192 + ws0) = l;
      cvt_split(f1, h, l); *(short8*)(d + ws1) = h; *(short8*)(d + 8192 + ws1) = l;
    }
    __syncthreads();

    for (int i = 0; i < NCH; ++i) {
      // 1) issue next-chunk x loads (HBM; consumed at step 3)
      float8 f0, f1;
      if (i + 1 < NCH) {
        const int o = (i + 1) * BK;
        f0 = *(const float8*)(xg + o);
        f1 = *(const float8*)(xg + o + 8);
      }
      // 2) issue all B loads for this chunk (L2-resident, coalesced 1KB each)
      short8 bh[NSTEP], bl[NSTEP];
#pragma unroll
      for (int kk = 0; kk < NSTEP; ++kk) {
        const char* p = wb + (size_t)(i * NSTEP + kk) * 8192;
        bh[kk] = *(const short8*)p;
        bl[kk] = *(const short8*)(p + 1024);
      }
      // 3) compute: pure ds_read + MFMA (order hh, hl, lh — verified numerics)
      const char* s = sm[i & 1];
#pragma unroll
      for (int kk = 0; kk < NSTEP; ++kk) {
        const int sa = (((kk * 4 + t4) ^ axr) << 4);
        short8 ah = *(const short8*)(s + ra + sa);
        short8 al = *(const short8*)(s + 8192 + ra + sa);
        acc = __builtin_amdgcn_mfma_f32_16x16x32_bf16(ah, bh[kk], acc, 0, 0, 0);
        acc = __builtin_amdgcn_mfma_f32_16x16x32_bf16(ah, bl[kk], acc, 0, 0, 0);
        acc = __builtin_amdgcn_mfma_f32_16x16x32_bf16(al, bh[kk], acc, 0, 0, 0);
      }
      // 4) convert + write next x chunk into the other buffer
      if (i + 1 < NCH) {
        char* d = sm[(i + 1) & 1];
        short8 h, l;
        cvt_split(f0, h, l); *(short8*)(d + ws0) = h; *(short8*)(d + 8192 + ws0) = l;
        cvt_split(f1, h, l); *(short8*)(d + ws1) = h; *(short8*)(d + 8192 + ws1) = l;
      }
      __syncthreads();
    }
  } else {
    // bf16 fallback (unexercised; register-direct, no d_ws dependency)
    const short* xp = (const short*)xv + (size_t)(r0 + lm) * D_DIM + t4 * 8;
    const short* wp = (const short*)wv + (size_t)(wave * 16 + lm) * D_DIM + t4 * 8;
    for (int k = 0; k < D_DIM; k += 64) {
      short8 a0 = *(const short8*)(xp + k);
      short8 b0 = *(const short8*)(wp + k);
      short8 a1 = *(const short8*)(xp + k + 32);
      short8 b1 = *(const short8*)(wp + k + 32);
      acc = __builtin_amdgcn_mfma_f32_16x16x32_bf16(a0, b0, acc, 0, 0, 0);
      acc = __builtin_amdgcn_mfma_f32_16x16x32_bf16(a1, b1, acc, 0, 0, 0);
    }
  }

  // C/D layout (m89-verified): col = lane&15 (expert), row = (lane>>4)*4 + reg
  {
    const int col   = wave * 16 + lm;
    const int rbase = t4 << 2;
#pragma unroll
    for (int r = 0; r < 4; ++r) lg[rbase + r][col] = acc[r];
  }
  __syncthreads();

  if (tid < BR) {
    const int row = tid;
    float m1 = -3.4e38f, m2 = -3.4e38f;
    int   i1 = 0, i2 = 0;
    for (int e = 0; e < E_DIM; ++e) {
      float be = isbf ? __bfloat162float(((const __hip_bfloat16*)bv)[e])
                      : ((const float*)bv)[e];
      float l = lg[row][e] + be;
      if (l > m1)      { m2 = m1; i2 = i1; m1 = l; i1 = e; }
      else if (l > m2) { m2 = l;  i2 = e; }
    }
    float s = 0.f;
    for (int e = 0; e < E_DIM; ++e) {
      float be = isbf ? __bfloat162float(((const __hip_bfloat16*)bv)[e])
                      : ((const float*)bv)[e];
      s += expf(lg[row][e] + be - m1);
    }
    const int gr = r0 + row;
    // outputs concatenated flat: [N*2 indices][N*2 weights], all as float32
    out[2 * gr]                  = (float)i1;
    out[2 * gr + 1]              = (float)i2;
    out[2 * N_ROWS + 2 * gr]     = 1.0f / s;                 // exp(m1-m1)/s
    out[2 * N_ROWS + 2 * gr + 1] = expf(m2 - m1) / s;
  }
}

extern "C" void kernel_launch(void* const* d_in, const int* in_sizes, int n_in,
                              void* d_out, int out_size, void* d_ws, size_t ws_size,
                              hipStream_t stream) {
  (void)in_sizes; (void)n_in; (void)out_size; (void)ws_size;
  // prep_w writes 1 MB of fragment-ordered split-bf16 W into d_ws;
  // same-stream ordering guarantees completion before router_kernel.
  prep_w<<<dim3(64), dim3(512), 0, stream>>>(d_in[0], d_in[1], d_ws);
  router_kernel<<<dim3(N_ROWS / BR), dim3(256), 0, stream>>>(
      d_in[0], d_in[1], d_in[2], d_ws, (float*)d_out);
}

// Round 6
// 218.031 us; speedup vs baseline: 1.0465x; 1.0465x over previous
//
#include <hip/hip_runtime.h>
#include <hip/hip_bf16.h>

#define N_ROWS 8192
#define D_DIM  4096
#define E_DIM  64
#define BR     16                 // rows per block
#define BK     256                // fp32 K elems per staged chunk
#define NCH    (D_DIM / BK)       // 16 chunks
#define NSTEP  (BK / 32)          // 8 K32-steps per chunk

typedef __attribute__((ext_vector_type(8))) short  short8;
typedef __attribute__((ext_vector_type(4))) float  floatx4;
typedef __attribute__((ext_vector_type(8))) float  float8;

// Split an fp32 vector into hi (RNE bf16) + lo (chopped bf16 of remainder).
// Bitwise-identical to the verified kernel -> identical numerics.
__device__ inline void cvt_split(const float8& f, short8& hi, short8& lo) {
#pragma unroll
  for (int j = 0; j < 8; ++j) {
    float x = f[j];
    unsigned int u  = __builtin_bit_cast(unsigned int, x);
    unsigned int rh = (u + 0x7FFFu + ((u >> 16) & 1u)) >> 16;  // RNE to bf16
    hi[j] = (short)rh;
    float hf = __builtin_bit_cast(float, rh << 16);
    float lf = x - hf;
    unsigned int ul = __builtin_bit_cast(unsigned int, lf);
    lo[j] = (short)(ul >> 16);                                  // chop
  }
}

// ---------------------------------------------------------------------------
// Prep kernel: convert W fp32 [64][4096] -> d_ws split-bf16 in FRAGMENT order.
// For K32-step s (0..127), expert tile e (0..3), plane p (hi/lo), lane l:
//   16B fragment = W rows e*16+(l&15), k = s*32+(l>>4)*8 .. +7
//   stored at ws + (s*8 + e*2 + p)*1024 + l*16          (total 1 MB)
// ---------------------------------------------------------------------------
__global__ __launch_bounds__(512) void prep_w(const void* __restrict__ xv,
                                              const void* __restrict__ wv,
                                              void* __restrict__ ws) {
  __shared__ int sflag;
  const int tid = threadIdx.x;
  if (tid < 64) {   // dtype probe (skip conversion if inputs are bf16)
    unsigned int v = ((const unsigned int*)xv)[(size_t)tid * 997];
    unsigned int e = (v >> 7) & 0xFFu;
    unsigned long long m = __ballot(e >= 100u && e <= 140u);
    if (tid == 0) sflag = (__popcll(m) > 32) ? 1 : 0;
  }
  __syncthreads();
  if (sflag) return;
  const int t    = blockIdx.x * 512 + tid;   // 64 blocks x 512 = 32768
  const int lane = t & 63;
  const int idx  = t >> 6;                    // s*4 + e
  const int s    = idx >> 2;
  const int e    = idx & 3;
  const int row  = e * 16 + (lane & 15);
  const int col  = s * 32 + (lane >> 4) * 8;
  float8 f = *(const float8*)((const float*)wv + (size_t)row * D_DIM + col);
  short8 h, l;
  cvt_split(f, h, l);
  char* d = (char*)ws + (size_t)idx * 2048 + lane * 16;
  *(short8*)d          = h;
  *(short8*)(d + 1024) = l;
}

// ---------------------------------------------------------------------------
// Main fused router: 512 blocks x 256 threads. Block = 16 rows, all 64
// experts. 4 waves: wave w -> expert tile w (16 experts), same 16 rows.
//
// Round-5: round-4 design WITHOUT __builtin_nontemporal_load (suspected
// container-kill trigger; two identical infra failures on that source).
//  * B fragments in NAMED registers (bh0..bh7, bl0..bl7 — no arrays, rule
//    #20), prefetched ONE CHUNK AHEAD: step kk consumes its fragment then
//    reloads it for chunk i+1. Prefetch distance = one full chunk of
//    LDS/MFMA pipe time (~1900 cy/CU) >> worst-case B-load latency.
//  * __launch_bounds__(256,2): VGPR budget 256 so the compiler has no
//    pressure to sink the B prefetch (round-3 VGPR=56 proved it sank them).
// x staging unchanged: split-bf16 LDS, double-buffered, slot-XOR swizzle.
// ---------------------------------------------------------------------------
__global__ __launch_bounds__(256, 2) void router_kernel(
    const void* __restrict__ xv, const void* __restrict__ wv,
    const void* __restrict__ bv, const void* __restrict__ wsv,
    float* __restrict__ out) {
  __shared__ __align__(16) char sm[2][16384];   // per buffer: xh 8K | xl 8K
  __shared__ float lg[BR][E_DIM + 4];
  __shared__ int   sflag;

  const int tid = threadIdx.x;

  if (tid < 64) {   // dtype probe
    unsigned int v = ((const unsigned int*)xv)[(size_t)tid * 997];
    unsigned int e = (v >> 7) & 0xFFu;
    unsigned long long m = __ballot(e >= 100u && e <= 140u);
    if (tid == 0) sflag = (__popcll(m) > 32) ? 1 : 0;
  }
  __syncthreads();
  const int isbf = sflag;

  const int wave = tid >> 6;            // expert tile 0..3
  const int lane = tid & 63;
  const int lm   = lane & 15;           // A: row-in-tile  B: expert-in-tile
  const int t4   = lane >> 4;           // k sub-slot within 32-wide K step
  const int r0   = blockIdx.x * BR;

  floatx4 acc = {0.f, 0.f, 0.f, 0.f};

  if (!isbf) {
    // staging geometry: thread -> 16 consecutive floats of one row
    const int srow = tid >> 4;          // 0..15
    const int sc   = tid & 15;          // 16-float col group
    const float* xg = (const float*)xv + (size_t)(r0 + srow) * D_DIM + sc * 16;
    const int ws0 = srow * 512 + ((( sc * 2     ) ^ (srow & 7)) << 4);
    const int ws1 = srow * 512 + ((( sc * 2 + 1 ) ^ (srow & 7)) << 4);
    // B fragment base for this wave's expert tile (+lane*16 per fragment)
    const char* wb = (const char*)wsv + (size_t)wave * 2048 + lane * 16;
    // A read base
    const int ra  = lm * 512;
    const int axr = lm & 7;

    // named B-fragment registers (NO arrays -> stay in VGPRs)
    short8 bh0, bh1, bh2, bh3, bh4, bh5, bh6, bh7;
    short8 bl0, bl1, bl2, bl3, bl4, bl5, bl6, bl7;

#define LDB(K, BASE)                                                       \
    bh##K = *(const short8*)((BASE) + (size_t)(K) * 8192);                 \
    bl##K = *(const short8*)((BASE) + (size_t)(K) * 8192 + 1024);

    // prologue: B frags for chunk 0, x chunk 0 staged to LDS
    LDB(0, wb) LDB(1, wb) LDB(2, wb) LDB(3, wb)
    LDB(4, wb) LDB(5, wb) LDB(6, wb) LDB(7, wb)
    {
      float8 f0 = *(const float8*)xg;
      float8 f1 = *(const float8*)(xg + 8);
      short8 h, l;
      char* d = sm[0];
      cvt_split(f0, h, l); *(short8*)(d + ws0) = h; *(short8*)(d + 8192 + ws0) = l;
      cvt_split(f1, h, l); *(short8*)(d + ws1) = h; *(short8*)(d + 8192 + ws1) = l;
    }
    __syncthreads();

    for (int i = 0; i < NCH; ++i) {
      // 1) issue next-chunk x loads (consumed at step 3)
      float8 f0, f1;
      if (i + 1 < NCH) {
        const int o = (i + 1) * BK;
        f0 = *(const float8*)(xg + o);
        f1 = *(const float8*)(xg + o + 8);
      }
      // 2) compute chunk i; each step reloads its B frag for chunk i+1
      //    (clamped at the tail: reloads chunk NCH-1's frags harmlessly)
      const char* s   = sm[i & 1];
      const char* wbn = wb + (size_t)((i + 1 < NCH) ? i + 1 : i) * (NSTEP * 8192);

#define STEP(K)                                                            \
    {                                                                      \
      const int sa = ((((K) << 2) + t4) ^ axr) << 4;                       \
      short8 ah = *(const short8*)(s + ra + sa);                           \
      short8 al = *(const short8*)(s + ra + 8192 + sa);                    \
      acc = __builtin_amdgcn_mfma_f32_16x16x32_bf16(ah, bh##K, acc, 0, 0, 0); \
      acc = __builtin_amdgcn_mfma_f32_16x16x32_bf16(ah, bl##K, acc, 0, 0, 0); \
      acc = __builtin_amdgcn_mfma_f32_16x16x32_bf16(al, bh##K, acc, 0, 0, 0); \
      LDB(K, wbn)                                                          \
    }

      STEP(0) STEP(1) STEP(2) STEP(3)
      STEP(4) STEP(5) STEP(6) STEP(7)

      // 3) convert + write next x chunk into the other buffer
      if (i + 1 < NCH) {
        char* d = sm[(i + 1) & 1];
        short8 h, l;
        cvt_split(f0, h, l); *(short8*)(d + ws0) = h; *(short8*)(d + 8192 + ws0) = l;
        cvt_split(f1, h, l); *(short8*)(d + ws1) = h; *(short8*)(d + 8192 + ws1) = l;
      }
      __syncthreads();
    }
#undef STEP
#undef LDB
  } else {
    // bf16 fallback (unexercised; register-direct, no d_ws dependency)
    const short* xp = (const short*)xv + (size_t)(r0 + lm) * D_DIM + t4 * 8;
    const short* wp = (const short*)wv + (size_t)(wave * 16 + lm) * D_DIM + t4 * 8;
    for (int k = 0; k < D_DIM; k += 64) {
      short8 a0 = *(const short8*)(xp + k);
      short8 b0 = *(const short8*)(wp + k);
      short8 a1 = *(const short8*)(xp + k + 32);
      short8 b1 = *(const short8*)(wp + k + 32);
      acc = __builtin_amdgcn_mfma_f32_16x16x32_bf16(a0, b0, acc, 0, 0, 0);
      acc = __builtin_amdgcn_mfma_f32_16x16x32_bf16(a1, b1, acc, 0, 0, 0);
    }
  }

  // C/D layout (m89-verified): col = lane&15 (expert), row = (lane>>4)*4 + reg
  {
    const int col   = wave * 16 + lm;
    const int rbase = t4 << 2;
#pragma unroll
    for (int r = 0; r < 4; ++r) lg[rbase + r][col] = acc[r];
  }
  __syncthreads();

  if (tid < BR) {
    const int row = tid;
    float m1 = -3.4e38f, m2 = -3.4e38f;
    int   i1 = 0, i2 = 0;
    for (int e = 0; e < E_DIM; ++e) {
      float be = isbf ? __bfloat162float(((const __hip_bfloat16*)bv)[e])
                      : ((const float*)bv)[e];
      float l = lg[row][e] + be;
      if (l > m1)      { m2 = m1; i2 = i1; m1 = l; i1 = e; }
      else if (l > m2) { m2 = l;  i2 = e; }
    }
    float s = 0.f;
    for (int e = 0; e < E_DIM; ++e) {
      float be = isbf ? __bfloat162float(((const __hip_bfloat16*)bv)[e])
                      : ((const float*)bv)[e];
      s += expf(lg[row][e] + be - m1);
    }
    const int gr = r0 + row;
    // outputs concatenated flat: [N*2 indices][N*2 weights], all as float32
    out[2 * gr]                  = (float)i1;
    out[2 * gr + 1]              = (float)i2;
    out[2 * N_ROWS + 2 * gr]     = 1.0f / s;                 // exp(m1-m1)/s
    out[2 * N_ROWS + 2 * gr + 1] = expf(m2 - m1) / s;
  }
}

extern "C" void kernel_launch(void* const* d_in, const int* in_sizes, int n_in,
                              void* d_out, int out_size, void* d_ws, size_t ws_size,
                              hipStream_t stream) {
  (void)in_sizes; (void)n_in; (void)out_size; (void)ws_size;
  // prep_w writes 1 MB of fragment-ordered split-bf16 W into d_ws;
  // same-stream ordering guarantees completion before router_kernel.
  prep_w<<<dim3(64), dim3(512), 0, stream>>>(d_in[0], d_in[1], d_ws);
  router_kernel<<<dim3(N_ROWS / BR), dim3(256), 0, stream>>>(
      d_in[0], d_in[1], d_in[2], d_ws, (float*)d_out);
}